// Round 1
// baseline (140.923 us; speedup 1.0000x reference)
//
#include <hip/hip_runtime.h>
#include <hip/hip_bf16.h>

#define DIM  512
#define FEAT 64
#define BATCH 2048

#define ROWS_PER_BLOCK 512
#define TILES_PER_WAVE 8   // ROWS_PER_BLOCK / (4 waves * 16 rows)

using bf16x8 = __attribute__((ext_vector_type(8))) short;
using f32x4  = __attribute__((ext_vector_type(4))) float;

__device__ inline short f2bf(float f) {
    // round-to-nearest-even fp32 -> bf16
    unsigned int u = __float_as_uint(f);
    u += 0x7fffu + ((u >> 16) & 1u);
    return (short)(u >> 16);
}

__device__ inline bf16x8 cvt8(float4 a, float4 b) {
    bf16x8 r;
    r[0] = f2bf(a.x); r[1] = f2bf(a.y); r[2] = f2bf(a.z); r[3] = f2bf(a.w);
    r[4] = f2bf(b.x); r[5] = f2bf(b.y); r[6] = f2bf(b.z); r[7] = f2bf(b.w);
    return r;
}

__global__ __launch_bounds__(256, 4)
void split_linear_kernel(const float* __restrict__ x,
                         const float* __restrict__ W,
                         const float* __restrict__ bias,
                         float* __restrict__ out)
{
    const int d    = blockIdx.y;
    const int b0   = blockIdx.x * ROWS_PER_BLOCK;
    const int tid  = threadIdx.x;
    const int wave = tid >> 6;
    const int lane = tid & 63;
    const int lr   = lane & 15;   // A-row / B-col / D-col within 16
    const int lk   = lane >> 4;   // k-group
    const int k0   = lk * 8;

    // ---- hoist B fragments (W_d) into registers: B[kstep][nt] ----
    // B[k][col] with col = lane&15, k = kstep*32 + (lane>>4)*8 + j
    // B[k][g] = W[d][g][k]  (g = nt*16 + lr), 8 contiguous f per lane.
    bf16x8 bfrag[2][4];
#pragma unroll
    for (int nt = 0; nt < 4; ++nt) {
        const int g = nt * 16 + lr;
        const float* wrow = W + ((size_t)d * FEAT + g) * FEAT;
#pragma unroll
        for (int ks = 0; ks < 2; ++ks) {
            const float* p = wrow + ks * 32 + k0;
            float4 w0 = *(const float4*)(p);
            float4 w1 = *(const float4*)(p + 4);
            bfrag[ks][nt] = cvt8(w0, w1);
        }
    }

    // bias: D col = nt*16 + lr
    float bv[4];
#pragma unroll
    for (int nt = 0; nt < 4; ++nt)
        bv[nt] = bias[(size_t)d * FEAT + nt * 16 + lr];

    // ---- main loop over 16-row tiles ----
    for (int t = 0; t < TILES_PER_WAVE; ++t) {
        const int tt  = t * 4 + wave;          // tile index in block
        const int arow = b0 + tt * 16 + lr;    // this lane's A row
        const float* xp = x + ((size_t)arow * DIM + d) * FEAT + k0;

        f32x4 acc[4] = {{0.f,0.f,0.f,0.f},{0.f,0.f,0.f,0.f},
                        {0.f,0.f,0.f,0.f},{0.f,0.f,0.f,0.f}};

#pragma unroll
        for (int ks = 0; ks < 2; ++ks) {
            float4 x0 = *(const float4*)(xp + ks * 32);
            float4 x1 = *(const float4*)(xp + ks * 32 + 4);
            bf16x8 afrag = cvt8(x0, x1);
#pragma unroll
            for (int nt = 0; nt < 4; ++nt)
                acc[nt] = __builtin_amdgcn_mfma_f32_16x16x32_bf16(
                              afrag, bfrag[ks][nt], acc[nt], 0, 0, 0);
        }

        // ---- epilogue: bias + store. D row = lk*4 + r, col = nt*16 + lr ----
        const int orow0 = b0 + tt * 16 + lk * 4;
#pragma unroll
        for (int nt = 0; nt < 4; ++nt) {
#pragma unroll
            for (int r = 0; r < 4; ++r) {
                out[((size_t)(orow0 + r) * DIM + d) * FEAT + nt * 16 + lr]
                    = acc[nt][r] + bv[nt];
            }
        }
    }
}

extern "C" void kernel_launch(void* const* d_in, const int* in_sizes, int n_in,
                              void* d_out, int out_size, void* d_ws, size_t ws_size,
                              hipStream_t stream) {
    const float* x    = (const float*)d_in[0];
    const float* W    = (const float*)d_in[1];
    const float* bias = (const float*)d_in[2];
    float* out        = (float*)d_out;

    dim3 grid(BATCH / ROWS_PER_BLOCK, DIM, 1);  // (4, 512)
    dim3 block(256, 1, 1);
    split_linear_kernel<<<grid, block, 0, stream>>>(x, W, bias, out);
}